// Round 2
// baseline (476.521 us; speedup 1.0000x reference)
//
#include <hip/hip_runtime.h>
#include <stdint.h>
#include <stddef.h>

#define TSEQ   2048
#define HDIM   512
#define NHEADS 8
#define HEADD  64
#define NVOCAB 32000
#define NROWS  4096   // B*T

typedef unsigned short ushort_t;
typedef __bf16 bf16x8 __attribute__((ext_vector_type(8)));
typedef float  f32x4  __attribute__((ext_vector_type(4)));
typedef unsigned short us8 __attribute__((ext_vector_type(8)));
typedef unsigned short us4 __attribute__((ext_vector_type(4)));
typedef unsigned short us2 __attribute__((ext_vector_type(2)));

__device__ __forceinline__ ushort_t f2bf(float f){
  union { float f; unsigned int u; } v; v.f = f;
  unsigned int u = v.u;
  u += 0x7FFFu + ((u >> 16) & 1u);   // RNE
  return (ushort_t)(u >> 16);
}

__device__ __forceinline__ void gload_lds16(const ushort_t* g, ushort_t* l){
  __builtin_amdgcn_global_load_lds(
      (const __attribute__((address_space(1))) void*)g,
      (__attribute__((address_space(3))) void*)l, 16, 0, 0);
}

// ---------------- fused f32 -> bf16 convert of all weights + bias concat ----------------
// ranges (in float4 units): Wprj 65536 | Wq 65536 | Wk 65536 | Wv 65536 | W1 65536 | W2 4096000
// then 384 float4 of bqkv concat (f32 passthrough)
#define CVT_N4   4423680   // 5*65536 + 4096000
#define CVT_TOT  4424064   // + 384
__global__ void cvt_all_kernel(const float* __restrict__ Wprj, const float* __restrict__ Wq,
                               const float* __restrict__ Wk,   const float* __restrict__ Wv,
                               const float* __restrict__ W1,   const float* __restrict__ W2,
                               const float* __restrict__ bq,   const float* __restrict__ bk,
                               const float* __restrict__ bv,
                               ushort_t* __restrict__ wdst, float* __restrict__ bqkv){
  int stride = gridDim.x * blockDim.x;
  for (int i = blockIdx.x * blockDim.x + threadIdx.x; i < CVT_TOT; i += stride){
    if (i < CVT_N4){
      const float* src; int j;
      if (i < 327680){                       // the five 512x512 weights
        int w = i >> 16;                     // 0..4
        j = i & 65535;
        src = (w == 0) ? Wprj : (w == 1) ? Wq : (w == 2) ? Wk : (w == 3) ? Wv : W1;
      } else {
        j = i - 327680;
        src = W2;
      }
      float4 f = ((const float4*)src)[j];
      us4 o;
      o[0] = f2bf(f.x); o[1] = f2bf(f.y); o[2] = f2bf(f.z); o[3] = f2bf(f.w);
      ((us4*)wdst)[i] = o;
    } else {
      int j = i - CVT_N4;                    // 0..383 float4 of bqkv
      const float* src = (j < 128) ? bq : (j < 256) ? bk : bv;
      int jj = j & 127;
      ((float4*)bqkv)[j] = ((const float4*)src)[jj];
    }
  }
}

// ---------------- embedding: x0 = tok[ix] + pos ----------------
__global__ void embed_kernel(const int* __restrict__ ixs, const float* __restrict__ tok,
                             const float* __restrict__ pos, ushort_t* __restrict__ x0){
  const int r = blockIdx.x;            // 0..4095 (b*T + t)
  const int t = r & (TSEQ - 1);
  const int ix = ixs[r];
  const int j = threadIdx.x;           // 0..255, 2 floats each
  const float2 a = ((const float2*)(tok + (size_t)ix * HDIM))[j];
  const float2 p = ((const float2*)(pos + (size_t)t * HDIM))[j];
  us2 o; o[0] = f2bf(a.x + p.x); o[1] = f2bf(a.y + p.y);
  *(us2*)(x0 + (size_t)r * HDIM + j * 2) = o;
}

// ---------------- GEMM: C[M,N] = A[M,K] @ W[N,K]^T (+bias)(+relu) ----------------
// m97 structure: 128x128 tile, BK=64, 4 waves (2x2 of 64x64), 16x16x32 bf16 MFMA
// Block mapping is BY-MAJOR: consecutive blocks share the same W column-panel
// (key for N=32000: W2 panel stays hot in L2 across the 32 co-resident row blocks;
// A (4 MB) is L2/L3-resident). Round-1 bx-major streamed W2 32x from L3 (~1 GB).
template<int HAS_BIAS, int RELU, int OUT_F32>
__global__ __launch_bounds__(256) void gemm_bt_kernel(
    const ushort_t* __restrict__ A, const ushort_t* __restrict__ W,
    const float* __restrict__ bias, void* __restrict__ outp,
    int M, int N, int K)
{
  __shared__ ushort_t As[128 * 64];
  __shared__ ushort_t Bs[128 * 64];
  const int tid  = threadIdx.x;
  const int wave = tid >> 6;
  const int lane = tid & 63;
  const int lr   = lane & 15;
  const int lg   = lane >> 4;
  const int nby  = M >> 7;
  const int by   = blockIdx.x % nby;
  const int bx   = blockIdx.x / nby;
  const int row0 = by << 7;
  const int col0 = bx << 7;
  const int wr   = wave >> 1, wc = wave & 1;

  f32x4 acc[4][4];
#pragma unroll
  for (int m = 0; m < 4; m++)
#pragma unroll
    for (int n = 0; n < 4; n++) acc[m][n] = (f32x4){0.f, 0.f, 0.f, 0.f};

  const int e    = tid * 8;        // element offset within a 4096-elem pass
  const int srow = e >> 6;         // 0..31
  const int scol = e & 63;
  const ushort_t* gA = A + (size_t)(row0 + srow) * K + scol;
  const ushort_t* gB = W + (size_t)(col0 + srow) * K + scol;
  const int ldsbase = wave * 512;  // elements; wave-uniform

  for (int kt = 0; kt < K; kt += 64){
#pragma unroll
    for (int p = 0; p < 4; p++){
      gload_lds16(gA + (size_t)(p * 32) * K + kt, &As[p * 2048 + ldsbase]);
      gload_lds16(gB + (size_t)(p * 32) * K + kt, &Bs[p * 2048 + ldsbase]);
    }
    __syncthreads();
#pragma unroll
    for (int kk = 0; kk < 64; kk += 32){
      bf16x8 af[4], bfr[4];
#pragma unroll
      for (int m = 0; m < 4; m++)
        af[m] = __builtin_bit_cast(bf16x8,
            *(const us8*)&As[(wr * 64 + m * 16 + lr) * 64 + kk + lg * 8]);
#pragma unroll
      for (int n = 0; n < 4; n++)
        bfr[n] = __builtin_bit_cast(bf16x8,
            *(const us8*)&Bs[(wc * 64 + n * 16 + lr) * 64 + kk + lg * 8]);
#pragma unroll
      for (int m = 0; m < 4; m++)
#pragma unroll
        for (int n = 0; n < 4; n++)
          acc[m][n] = __builtin_amdgcn_mfma_f32_16x16x32_bf16(af[m], bfr[n], acc[m][n], 0, 0, 0);
    }
    __syncthreads();
  }

#pragma unroll
  for (int n = 0; n < 4; n++){
    const int col = col0 + wc * 64 + n * 16 + lr;
    float bv = 0.f;
    if (HAS_BIAS) bv = bias[col];
#pragma unroll
    for (int m = 0; m < 4; m++){
      const int rowb = row0 + wr * 64 + m * 16 + lg * 4;
#pragma unroll
      for (int r = 0; r < 4; r++){
        float vv = acc[m][n][r] + bv;
        if (RELU) vv = fmaxf(vv, 0.f);
        const size_t o = (size_t)(rowb + r) * N + col;
        if (OUT_F32) ((float*)outp)[o] = vv;
        else         ((ushort_t*)outp)[o] = f2bf(vv);
      }
    }
  }
}

// ---------------- fused causal flash attention ----------------
// block = 4 waves; wave w owns 16 q-rows of a 64-row q-tile. K/V tiles of 64.
__global__ __launch_bounds__(256) void attn_kernel(
    const ushort_t* __restrict__ qkv, ushort_t* __restrict__ y)
{
  __shared__ ushort_t Ks[64 * 64];
  __shared__ ushort_t Vt[64 * 64];     // transposed: [d][key]
  __shared__ ushort_t Ps[4][16 * 64];
  const int qt   = blockIdx.x;         // 0..31
  const int hb   = blockIdx.y;         // 0..15
  const int b    = hb >> 3;
  const int h    = hb & 7;
  const int tid  = threadIdx.x;
  const int wave = tid >> 6, lane = tid & 63;
  const int lr   = lane & 15, lg = lane >> 4;
  const int ld   = 3 * HDIM;           // qkv row stride = 1536
  const size_t rowbase = (size_t)b * TSEQ;
  const ushort_t* kb = qkv + HDIM;
  const ushort_t* vb = qkv + 2 * HDIM;

  const int qrow = qt * 64 + wave * 16 + lr;
  const ushort_t* qp = qkv + (rowbase + qrow) * ld + h * HEADD;
  bf16x8 qf[2];
  qf[0] = __builtin_bit_cast(bf16x8, *(const us8*)&qp[lg * 8]);
  qf[1] = __builtin_bit_cast(bf16x8, *(const us8*)&qp[32 + lg * 8]);

  float m_run[4], l_run[4];
  f32x4 acc_o[4];
#pragma unroll
  for (int i = 0; i < 4; i++){ m_run[i] = -1e30f; l_run[i] = 0.f; acc_o[i] = (f32x4){0,0,0,0}; }

  const int e    = tid * 8;
  const int srow = e >> 6;
  const int scol = e & 63;
  const float scale = 0.04419417382415922f;   // 1/sqrt(512) (full H per reference!)

  for (int kt = 0; kt <= qt; ++kt){
    const ushort_t* gK = kb + (rowbase + kt * 64 + srow) * ld + h * HEADD + scol;
    gload_lds16(gK,                     &Ks[wave * 512]);
    gload_lds16(gK + (size_t)32 * ld,   &Ks[2048 + wave * 512]);
    const ushort_t* gV = vb + (rowbase + kt * 64 + srow) * ld + h * HEADD + scol;
    us8 v0 = *(const us8*)gV;
    us8 v1 = *(const us8*)(gV + (size_t)32 * ld);
#pragma unroll
    for (int j = 0; j < 8; j++){
      Vt[(scol + j) * 64 + srow]      = v0[j];
      Vt[(scol + j) * 64 + srow + 32] = v1[j];
    }
    __syncthreads();

    // S = Q @ K^T  (C layout: col=key=lane&15 within frag n, row=q=lg*4+r)
    f32x4 s[4];
#pragma unroll
    for (int n = 0; n < 4; n++){
      s[n] = (f32x4){0, 0, 0, 0};
#pragma unroll
      for (int ks = 0; ks < 2; ks++){
        bf16x8 kf = __builtin_bit_cast(bf16x8,
            *(const us8*)&Ks[(n * 16 + lr) * 64 + ks * 32 + lg * 8]);
        s[n] = __builtin_amdgcn_mfma_f32_16x16x32_bf16(qf[ks], kf, s[n], 0, 0, 0);
      }
    }

    float sv[4][4];
    float tmax[4] = {-1e30f, -1e30f, -1e30f, -1e30f};
    const bool diag = (kt == qt);
#pragma unroll
    for (int n = 0; n < 4; n++)
#pragma unroll
      for (int r = 0; r < 4; r++){
        float x = s[n][r] * scale;
        if (diag && (n * 16 + lr) > (wave * 16 + lg * 4 + r)) x = -1e30f;
        sv[n][r] = x;
        tmax[r] = fmaxf(tmax[r], x);
      }
#pragma unroll
    for (int off = 1; off < 16; off <<= 1)
#pragma unroll
      for (int r = 0; r < 4; r++) tmax[r] = fmaxf(tmax[r], __shfl_xor(tmax[r], off));

    float alpha[4], psum[4];
#pragma unroll
    for (int r = 0; r < 4; r++){
      float mn = fmaxf(m_run[r], tmax[r]);
      alpha[r] = __expf(m_run[r] - mn);
      m_run[r] = mn;
      psum[r] = 0.f;
    }
    float p[4][4];
#pragma unroll
    for (int n = 0; n < 4; n++)
#pragma unroll
      for (int r = 0; r < 4; r++){ p[n][r] = __expf(sv[n][r] - m_run[r]); psum[r] += p[n][r]; }
#pragma unroll
    for (int off = 1; off < 16; off <<= 1)
#pragma unroll
      for (int r = 0; r < 4; r++) psum[r] += __shfl_xor(psum[r], off);
#pragma unroll
    for (int r = 0; r < 4; r++) l_run[r] = l_run[r] * alpha[r] + psum[r];
#pragma unroll
    for (int nd = 0; nd < 4; nd++)
#pragma unroll
      for (int r = 0; r < 4; r++) acc_o[nd][r] *= alpha[r];

    // P (C-layout) -> LDS -> A-layout fragments
#pragma unroll
    for (int n = 0; n < 4; n++)
#pragma unroll
      for (int r = 0; r < 4; r++)
        Ps[wave][(lg * 4 + r) * 64 + n * 16 + lr] = f2bf(p[n][r]);
    asm volatile("s_waitcnt lgkmcnt(0)" ::: "memory");
    bf16x8 pa[2];
    pa[0] = __builtin_bit_cast(bf16x8, *(const us8*)&Ps[wave][lr * 64 + lg * 8]);
    pa[1] = __builtin_bit_cast(bf16x8, *(const us8*)&Ps[wave][lr * 64 + 32 + lg * 8]);
#pragma unroll
    for (int nd = 0; nd < 4; nd++)
#pragma unroll
      for (int ks = 0; ks < 2; ks++){
        bf16x8 vf = __builtin_bit_cast(bf16x8,
            *(const us8*)&Vt[(nd * 16 + lr) * 64 + ks * 32 + lg * 8]);
        acc_o[nd] = __builtin_amdgcn_mfma_f32_16x16x32_bf16(pa[ks], vf, acc_o[nd], 0, 0, 0);
      }
    __syncthreads();
  }

  float inv[4];
#pragma unroll
  for (int r = 0; r < 4; r++) inv[r] = 1.f / l_run[r];
#pragma unroll
  for (int nd = 0; nd < 4; nd++)
#pragma unroll
    for (int r = 0; r < 4; r++){
      const int row_t = qt * 64 + wave * 16 + lg * 4 + r;
      y[(rowbase + row_t) * HDIM + h * HEADD + nd * 16 + lr] = f2bf(acc_o[nd][r] * inv[r]);
    }
}

// ---------------- launch ----------------
extern "C" void kernel_launch(void* const* d_in, const int* in_sizes, int n_in,
                              void* d_out, int out_size, void* d_ws, size_t ws_size,
                              hipStream_t stream)
{
  const int*   ixs  = (const int*)  d_in[0];
  const float* tok  = (const float*)d_in[1];
  const float* pos  = (const float*)d_in[2];
  const float* Wprj = (const float*)d_in[3];
  const float* Wq   = (const float*)d_in[4];
  const float* bq_  = (const float*)d_in[5];
  const float* Wk   = (const float*)d_in[6];
  const float* bk_  = (const float*)d_in[7];
  const float* Wv   = (const float*)d_in[8];
  const float* bv_  = (const float*)d_in[9];
  const float* W1   = (const float*)d_in[10];
  const float* b1_  = (const float*)d_in[11];
  const float* W2   = (const float*)d_in[12];
  const float* b2_  = (const float*)d_in[13];
  float* out = (float*)d_out;

  ushort_t* ws    = (ushort_t*)d_ws;
  ushort_t* x0    = ws;                          // 4096*512
  ushort_t* x1    = x0    + 2097152;
  ushort_t* qkv   = x1    + 2097152;             // 4096*1536
  ushort_t* yb    = qkv   + 6291456;
  ushort_t* h1b   = yb    + 2097152;
  // fused weight arena: [Wprj|Wq|Wk|Wv|W1|W2] contiguous bf16
  ushort_t* wprjb = h1b   + 2097152;             // 512*512
  ushort_t* wqkvb = wprjb + 262144;              // 3*512*512
  ushort_t* w1b   = wqkvb + 786432;
  ushort_t* w2b   = w1b   + 262144;              // 32000*512
  float*    bqkv  = (float*)(w2b + 16384000);    // 1536 f32

  // one fused kernel: all weight converts + bias concat (replaces 6 cvt + 3 memcpy)
  cvt_all_kernel<<<2048, 256, 0, stream>>>(Wprj, Wq, Wk, Wv, W1, W2,
                                           bq_, bk_, bv_, wprjb, bqkv);

  embed_kernel<<<NROWS, 256, 0, stream>>>(ixs, tok, pos, x0);

  // x1 = x0 @ Wprj^T
  gemm_bt_kernel<0,0,0><<<32 * 4,   256, 0, stream>>>(x0,  wprjb, nullptr, x1,  NROWS, 512,   512);
  // qkv (fused q|k|v, N=1536)
  gemm_bt_kernel<1,0,0><<<32 * 12,  256, 0, stream>>>(x1,  wqkvb, bqkv,    qkv, NROWS, 1536,  512);
  // attention
  attn_kernel<<<dim3(32, 16), 256, 0, stream>>>(qkv, yb);
  // h1 = relu(y @ W1^T + b1)
  gemm_bt_kernel<1,1,0><<<32 * 4,   256, 0, stream>>>(yb,  w1b,   b1_,     h1b, NROWS, 512,   512);
  // out = relu(h1 @ W2^T + b2)  -> f32
  gemm_bt_kernel<1,1,1><<<32 * 250, 256, 0, stream>>>(h1b, w2b,   b2_,     out, NROWS, NVOCAB, 512);
}

// Round 3
// 402.554 us; speedup vs baseline: 1.1837x; 1.1837x over previous
//
#include <hip/hip_runtime.h>
#include <stdint.h>
#include <stddef.h>

#define TSEQ   2048
#define HDIM   512
#define NHEADS 8
#define HEADD  64
#define NVOCAB 32000
#define NROWS  4096   // B*T

typedef unsigned short ushort_t;
typedef __bf16 bf16x8 __attribute__((ext_vector_type(8)));
typedef float  f32x4  __attribute__((ext_vector_type(4)));
typedef unsigned short us8 __attribute__((ext_vector_type(8)));
typedef unsigned short us4 __attribute__((ext_vector_type(4)));
typedef unsigned short us2 __attribute__((ext_vector_type(2)));

__device__ __forceinline__ ushort_t f2bf(float f){
  union { float f; unsigned int u; } v; v.f = f;
  unsigned int u = v.u;
  u += 0x7FFFu + ((u >> 16) & 1u);   // RNE
  return (ushort_t)(u >> 16);
}

__device__ __forceinline__ void gload_lds16(const ushort_t* g, ushort_t* l){
  __builtin_amdgcn_global_load_lds(
      (const __attribute__((address_space(1))) void*)g,
      (__attribute__((address_space(3))) void*)l, 16, 0, 0);
}

// ---------------- fused f32 -> bf16 convert of all weights + bias concat ----------------
#define CVT_N4   4423680   // 5*65536 + 4096000
#define CVT_TOT  4424064   // + 384
__global__ void cvt_all_kernel(const float* __restrict__ Wprj, const float* __restrict__ Wq,
                               const float* __restrict__ Wk,   const float* __restrict__ Wv,
                               const float* __restrict__ W1,   const float* __restrict__ W2,
                               const float* __restrict__ bq,   const float* __restrict__ bk,
                               const float* __restrict__ bv,
                               ushort_t* __restrict__ wdst, float* __restrict__ bqkv){
  int stride = gridDim.x * blockDim.x;
  for (int i = blockIdx.x * blockDim.x + threadIdx.x; i < CVT_TOT; i += stride){
    if (i < CVT_N4){
      const float* src; int j;
      if (i < 327680){                       // the five 512x512 weights
        int w = i >> 16;                     // 0..4
        j = i & 65535;
        src = (w == 0) ? Wprj : (w == 1) ? Wq : (w == 2) ? Wk : (w == 3) ? Wv : W1;
      } else {
        j = i - 327680;
        src = W2;
      }
      float4 f = ((const float4*)src)[j];
      us4 o;
      o[0] = f2bf(f.x); o[1] = f2bf(f.y); o[2] = f2bf(f.z); o[3] = f2bf(f.w);
      ((us4*)wdst)[i] = o;
    } else {
      int j = i - CVT_N4;                    // 0..383 float4 of bqkv
      const float* src = (j < 128) ? bq : (j < 256) ? bk : bv;
      int jj = j & 127;
      ((float4*)bqkv)[j] = ((const float4*)src)[jj];
    }
  }
}

// ---------------- embedding: x0 = tok[ix] + pos ----------------
__global__ void embed_kernel(const int* __restrict__ ixs, const float* __restrict__ tok,
                             const float* __restrict__ pos, ushort_t* __restrict__ x0){
  const int r = blockIdx.x;            // 0..4095 (b*T + t)
  const int t = r & (TSEQ - 1);
  const int ix = ixs[r];
  const int j = threadIdx.x;           // 0..255, 2 floats each
  const float2 a = ((const float2*)(tok + (size_t)ix * HDIM))[j];
  const float2 p = ((const float2*)(pos + (size_t)t * HDIM))[j];
  us2 o; o[0] = f2bf(a.x + p.x); o[1] = f2bf(a.y + p.y);
  *(us2*)(x0 + (size_t)r * HDIM + j * 2) = o;
}

// ---------------- small GEMM (m97 structure): C[M,N] = A @ W^T (+bias)(+relu) ----------------
template<int HAS_BIAS, int RELU, int OUT_F32>
__global__ __launch_bounds__(256) void gemm_bt_kernel(
    const ushort_t* __restrict__ A, const ushort_t* __restrict__ W,
    const float* __restrict__ bias, void* __restrict__ outp,
    int M, int N, int K)
{
  __shared__ ushort_t As[128 * 64];
  __shared__ ushort_t Bs[128 * 64];
  const int tid  = threadIdx.x;
  const int wave = tid >> 6;
  const int lane = tid & 63;
  const int lr   = lane & 15;
  const int lg   = lane >> 4;
  const int nby  = M >> 7;
  const int by   = blockIdx.x % nby;
  const int bx   = blockIdx.x / nby;
  const int row0 = by << 7;
  const int col0 = bx << 7;
  const int wr   = wave >> 1, wc = wave & 1;

  f32x4 acc[4][4];
#pragma unroll
  for (int m = 0; m < 4; m++)
#pragma unroll
    for (int n = 0; n < 4; n++) acc[m][n] = (f32x4){0.f, 0.f, 0.f, 0.f};

  const int e    = tid * 8;
  const int srow = e >> 6;
  const int scol = e & 63;
  const ushort_t* gA = A + (size_t)(row0 + srow) * K + scol;
  const ushort_t* gB = W + (size_t)(col0 + srow) * K + scol;
  const int ldsbase = wave * 512;

  for (int kt = 0; kt < K; kt += 64){
#pragma unroll
    for (int p = 0; p < 4; p++){
      gload_lds16(gA + (size_t)(p * 32) * K + kt, &As[p * 2048 + ldsbase]);
      gload_lds16(gB + (size_t)(p * 32) * K + kt, &Bs[p * 2048 + ldsbase]);
    }
    __syncthreads();
#pragma unroll
    for (int kk = 0; kk < 64; kk += 32){
      bf16x8 af[4], bfr[4];
#pragma unroll
      for (int m = 0; m < 4; m++)
        af[m] = __builtin_bit_cast(bf16x8,
            *(const us8*)&As[(wr * 64 + m * 16 + lr) * 64 + kk + lg * 8]);
#pragma unroll
      for (int n = 0; n < 4; n++)
        bfr[n] = __builtin_bit_cast(bf16x8,
            *(const us8*)&Bs[(wc * 64 + n * 16 + lr) * 64 + kk + lg * 8]);
#pragma unroll
      for (int m = 0; m < 4; m++)
#pragma unroll
        for (int n = 0; n < 4; n++)
          acc[m][n] = __builtin_amdgcn_mfma_f32_16x16x32_bf16(af[m], bfr[n], acc[m][n], 0, 0, 0);
    }
    __syncthreads();
  }

#pragma unroll
  for (int n = 0; n < 4; n++){
    const int col = col0 + wc * 64 + n * 16 + lr;
    float bv = 0.f;
    if (HAS_BIAS) bv = bias[col];
#pragma unroll
    for (int m = 0; m < 4; m++){
      const int rowb = row0 + wr * 64 + m * 16 + lg * 4;
#pragma unroll
      for (int r = 0; r < 4; r++){
        float vv = acc[m][n][r] + bv;
        if (RELU) vv = fmaxf(vv, 0.f);
        const size_t o = (size_t)(rowb + r) * N + col;
        if (OUT_F32) ((float*)outp)[o] = vv;
        else         ((ushort_t*)outp)[o] = f2bf(vv);
      }
    }
  }
}

// ---------------- 8-phase-style 256x256 GEMM for the big vocab matmul ----------------
// out = relu(A[M,K=512] @ W[N,K]^T + bias), f32 out.
// 8 waves (2M x 4N), per-wave 128x64 output, BK=32, 16 K-tiles.
// Triple-buffered LDS (96 KB), depth-2 tile prefetch, counted vmcnt(4) (never 0
// in steady state), raw s_barrier, setprio around MFMA, T2-style chunk swizzle
// (16B chunk ^= row&3, same involution on pre-swizzled global source and ds_read;
// LDS dest stays linear for global_load_lds per m104/m173).
#define NKT 16
__global__ __launch_bounds__(512, 2) void gemm_big_kernel(
    const ushort_t* __restrict__ A, const ushort_t* __restrict__ W,
    const float* __restrict__ bias, float* __restrict__ outp,
    int M, int N, int K)
{
  __shared__ ushort_t Asb[3][256 * 32];
  __shared__ ushort_t Bsb[3][256 * 32];
  const int tid  = threadIdx.x;
  const int wave = tid >> 6;            // 0..7
  const int lane = tid & 63;
  const int lr   = lane & 15;
  const int lg   = lane >> 4;
  const int wr   = wave >> 2;           // 0..1 (M)
  const int wc   = wave & 3;            // 0..3 (N)
  const int nby  = M >> 8;              // 16
  const int by   = blockIdx.x % nby;
  const int bx   = blockIdx.x / nby;
  const int row0 = by << 8;
  const int col0 = bx << 8;

  // staging geometry: thread covers LDS row rA (and rA+128), 16B chunk (tid&3),
  // source column chunk is swizzled by row&3
  const int rA   = tid >> 2;            // 0..127
  const int csw  = ((tid & 3) ^ (rA & 3)) * 8;   // element offset of swizzled chunk
  const int swzc = (lg ^ (lr & 3)) * 8;          // ds_read side (row&3 == lr&3)

  f32x4 acc[8][4];
#pragma unroll
  for (int m = 0; m < 8; m++)
#pragma unroll
    for (int n = 0; n < 4; n++) acc[m][n] = (f32x4){0.f, 0.f, 0.f, 0.f};

  // ---- prologue: stage tiles 0 and 1, wait for tile 0 ----
  {
    const ushort_t* gA = A + (size_t)(row0 + rA) * K + csw;
    const ushort_t* gW = W + (size_t)(col0 + rA) * K + csw;
#pragma unroll
    for (int t = 0; t < 2; t++){
      gload_lds16(gA + t * 32,                       &Asb[t][wave * 512]);
      gload_lds16(gA + (size_t)128 * K + t * 32,     &Asb[t][4096 + wave * 512]);
      gload_lds16(gW + t * 32,                       &Bsb[t][wave * 512]);
      gload_lds16(gW + (size_t)128 * K + t * 32,     &Bsb[t][4096 + wave * 512]);
    }
  }
  asm volatile("s_waitcnt vmcnt(4)" ::: "memory");
  __builtin_amdgcn_s_barrier();

  for (int t = 0; t < NKT; ++t){
    const ushort_t* Ac = &Asb[t % 3][0];
    const ushort_t* Bc = &Bsb[t % 3][0];
    ushort_t* An = &Asb[(t + 2) % 3][0];
    ushort_t* Bn = &Bsb[(t + 2) % 3][0];
    const bool pf = (t + 2 < NKT);
    const int kg = (t + 2) * 32;

    // ---------- phase 0: B-frags + A-frags m0..3 ; stage A of tile t+2 ----------
    bf16x8 bfr[4], af[4];
#pragma unroll
    for (int n = 0; n < 4; n++)
      bfr[n] = __builtin_bit_cast(bf16x8,
          *(const us8*)&Bc[(wc * 64 + n * 16 + lr) * 32 + swzc]);
#pragma unroll
    for (int q = 0; q < 4; q++)
      af[q] = __builtin_bit_cast(bf16x8,
          *(const us8*)&Ac[(wr * 128 + q * 16 + lr) * 32 + swzc]);
    if (pf){
      gload_lds16(A + (size_t)(row0 + rA) * K + kg + csw,       An + wave * 512);
      gload_lds16(A + (size_t)(row0 + rA + 128) * K + kg + csw, An + 4096 + wave * 512);
    }
    __builtin_amdgcn_s_barrier();
    asm volatile("s_waitcnt lgkmcnt(0)" ::: "memory");
    __builtin_amdgcn_sched_barrier(0);
    __builtin_amdgcn_s_setprio(1);
#pragma unroll
    for (int q = 0; q < 4; q++)
#pragma unroll
      for (int n = 0; n < 4; n++)
        acc[q][n] = __builtin_amdgcn_mfma_f32_16x16x32_bf16(af[q], bfr[n], acc[q][n], 0, 0, 0);
    __builtin_amdgcn_s_setprio(0);
    __builtin_amdgcn_sched_barrier(0);
    __builtin_amdgcn_s_barrier();

    // ---------- phase 1: A-frags m4..7 ; stage B of tile t+2 ----------
#pragma unroll
    for (int q = 0; q < 4; q++)
      af[q] = __builtin_bit_cast(bf16x8,
          *(const us8*)&Ac[(wr * 128 + (q + 4) * 16 + lr) * 32 + swzc]);
    if (pf){
      gload_lds16(W + (size_t)(col0 + rA) * K + kg + csw,       Bn + wave * 512);
      gload_lds16(W + (size_t)(col0 + rA + 128) * K + kg + csw, Bn + 4096 + wave * 512);
    }
    __builtin_amdgcn_s_barrier();
    asm volatile("s_waitcnt lgkmcnt(0)" ::: "memory");
    __builtin_amdgcn_sched_barrier(0);
    __builtin_amdgcn_s_setprio(1);
#pragma unroll
    for (int q = 0; q < 4; q++)
#pragma unroll
      for (int n = 0; n < 4; n++)
        acc[q + 4][n] = __builtin_amdgcn_mfma_f32_16x16x32_bf16(af[q], bfr[n], acc[q + 4][n], 0, 0, 0);
    __builtin_amdgcn_s_setprio(0);
    __builtin_amdgcn_sched_barrier(0);
    if (t < NKT - 2) { asm volatile("s_waitcnt vmcnt(4)" ::: "memory"); }
    else             { asm volatile("s_waitcnt vmcnt(0)" ::: "memory"); }
    __builtin_amdgcn_s_barrier();
  }

  // ---- epilogue ----
  float bvv[4];
#pragma unroll
  for (int n = 0; n < 4; n++) bvv[n] = bias[col0 + wc * 64 + n * 16 + lr];
#pragma unroll
  for (int m = 0; m < 8; m++)
#pragma unroll
    for (int n = 0; n < 4; n++){
      const size_t o0 = (size_t)(row0 + wr * 128 + m * 16 + lg * 4) * N
                      + (col0 + wc * 64 + n * 16 + lr);
#pragma unroll
      for (int r = 0; r < 4; r++)
        outp[o0 + (size_t)r * N] = fmaxf(acc[m][n][r] + bvv[n], 0.f);
    }
}

// ---------------- fused causal flash attention ----------------
__global__ __launch_bounds__(256) void attn_kernel(
    const ushort_t* __restrict__ qkv, ushort_t* __restrict__ y)
{
  __shared__ ushort_t Ks[64 * 64];
  __shared__ ushort_t Vt[64 * 64];     // transposed: [d][key]
  __shared__ ushort_t Ps[4][16 * 64];
  const int qt   = blockIdx.x;
  const int hb   = blockIdx.y;
  const int b    = hb >> 3;
  const int h    = hb & 7;
  const int tid  = threadIdx.x;
  const int wave = tid >> 6, lane = tid & 63;
  const int lr   = lane & 15, lg = lane >> 4;
  const int ld   = 3 * HDIM;
  const size_t rowbase = (size_t)b * TSEQ;
  const ushort_t* kb = qkv + HDIM;
  const ushort_t* vb = qkv + 2 * HDIM;

  const int qrow = qt * 64 + wave * 16 + lr;
  const ushort_t* qp = qkv + (rowbase + qrow) * ld + h * HEADD;
  bf16x8 qf[2];
  qf[0] = __builtin_bit_cast(bf16x8, *(const us8*)&qp[lg * 8]);
  qf[1] = __builtin_bit_cast(bf16x8, *(const us8*)&qp[32 + lg * 8]);

  float m_run[4], l_run[4];
  f32x4 acc_o[4];
#pragma unroll
  for (int i = 0; i < 4; i++){ m_run[i] = -1e30f; l_run[i] = 0.f; acc_o[i] = (f32x4){0,0,0,0}; }

  const int e    = tid * 8;
  const int srow = e >> 6;
  const int scol = e & 63;
  const float scale = 0.04419417382415922f;   // 1/sqrt(512) (full H per reference!)

  for (int kt = 0; kt <= qt; ++kt){
    const ushort_t* gK = kb + (rowbase + kt * 64 + srow) * ld + h * HEADD + scol;
    gload_lds16(gK,                     &Ks[wave * 512]);
    gload_lds16(gK + (size_t)32 * ld,   &Ks[2048 + wave * 512]);
    const ushort_t* gV = vb + (rowbase + kt * 64 + srow) * ld + h * HEADD + scol;
    us8 v0 = *(const us8*)gV;
    us8 v1 = *(const us8*)(gV + (size_t)32 * ld);
#pragma unroll
    for (int j = 0; j < 8; j++){
      Vt[(scol + j) * 64 + srow]      = v0[j];
      Vt[(scol + j) * 64 + srow + 32] = v1[j];
    }
    __syncthreads();

    f32x4 s[4];
#pragma unroll
    for (int n = 0; n < 4; n++){
      s[n] = (f32x4){0, 0, 0, 0};
#pragma unroll
      for (int ks = 0; ks < 2; ks++){
        bf16x8 kf = __builtin_bit_cast(bf16x8,
            *(const us8*)&Ks[(n * 16 + lr) * 64 + ks * 32 + lg * 8]);
        s[n] = __builtin_amdgcn_mfma_f32_16x16x32_bf16(qf[ks], kf, s[n], 0, 0, 0);
      }
    }

    float sv[4][4];
    float tmax[4] = {-1e30f, -1e30f, -1e30f, -1e30f};
    const bool diag = (kt == qt);
#pragma unroll
    for (int n = 0; n < 4; n++)
#pragma unroll
      for (int r = 0; r < 4; r++){
        float x = s[n][r] * scale;
        if (diag && (n * 16 + lr) > (wave * 16 + lg * 4 + r)) x = -1e30f;
        sv[n][r] = x;
        tmax[r] = fmaxf(tmax[r], x);
      }
#pragma unroll
    for (int off = 1; off < 16; off <<= 1)
#pragma unroll
      for (int r = 0; r < 4; r++) tmax[r] = fmaxf(tmax[r], __shfl_xor(tmax[r], off));

    float alpha[4], psum[4];
#pragma unroll
    for (int r = 0; r < 4; r++){
      float mn = fmaxf(m_run[r], tmax[r]);
      alpha[r] = __expf(m_run[r] - mn);
      m_run[r] = mn;
      psum[r] = 0.f;
    }
    float p[4][4];
#pragma unroll
    for (int n = 0; n < 4; n++)
#pragma unroll
      for (int r = 0; r < 4; r++){ p[n][r] = __expf(sv[n][r] - m_run[r]); psum[r] += p[n][r]; }
#pragma unroll
    for (int off = 1; off < 16; off <<= 1)
#pragma unroll
      for (int r = 0; r < 4; r++) psum[r] += __shfl_xor(psum[r], off);
#pragma unroll
    for (int r = 0; r < 4; r++) l_run[r] = l_run[r] * alpha[r] + psum[r];
#pragma unroll
    for (int nd = 0; nd < 4; nd++)
#pragma unroll
      for (int r = 0; r < 4; r++) acc_o[nd][r] *= alpha[r];

#pragma unroll
    for (int n = 0; n < 4; n++)
#pragma unroll
      for (int r = 0; r < 4; r++)
        Ps[wave][(lg * 4 + r) * 64 + n * 16 + lr] = f2bf(p[n][r]);
    asm volatile("s_waitcnt lgkmcnt(0)" ::: "memory");
    bf16x8 pa[2];
    pa[0] = __builtin_bit_cast(bf16x8, *(const us8*)&Ps[wave][lr * 64 + lg * 8]);
    pa[1] = __builtin_bit_cast(bf16x8, *(const us8*)&Ps[wave][lr * 64 + 32 + lg * 8]);
#pragma unroll
    for (int nd = 0; nd < 4; nd++)
#pragma unroll
      for (int ks = 0; ks < 2; ks++){
        bf16x8 vf = __builtin_bit_cast(bf16x8,
            *(const us8*)&Vt[(nd * 16 + lr) * 64 + ks * 32 + lg * 8]);
        acc_o[nd] = __builtin_amdgcn_mfma_f32_16x16x32_bf16(pa[ks], vf, acc_o[nd], 0, 0, 0);
      }
    __syncthreads();
  }

  float inv[4];
#pragma unroll
  for (int r = 0; r < 4; r++) inv[r] = 1.f / l_run[r];
#pragma unroll
  for (int nd = 0; nd < 4; nd++)
#pragma unroll
    for (int r = 0; r < 4; r++){
      const int row_t = qt * 64 + wave * 16 + lg * 4 + r;
      y[(rowbase + row_t) * HDIM + h * HEADD + nd * 16 + lr] = f2bf(acc_o[nd][r] * inv[r]);
    }
}

// ---------------- launch ----------------
extern "C" void kernel_launch(void* const* d_in, const int* in_sizes, int n_in,
                              void* d_out, int out_size, void* d_ws, size_t ws_size,
                              hipStream_t stream)
{
  const int*   ixs  = (const int*)  d_in[0];
  const float* tok  = (const float*)d_in[1];
  const float* pos  = (const float*)d_in[2];
  const float* Wprj = (const float*)d_in[3];
  const float* Wq   = (const float*)d_in[4];
  const float* bq_  = (const float*)d_in[5];
  const float* Wk   = (const float*)d_in[6];
  const float* bk_  = (const float*)d_in[7];
  const float* Wv   = (const float*)d_in[8];
  const float* bv_  = (const float*)d_in[9];
  const float* W1   = (const float*)d_in[10];
  const float* b1_  = (const float*)d_in[11];
  const float* W2   = (const float*)d_in[12];
  const float* b2_  = (const float*)d_in[13];
  float* out = (float*)d_out;

  ushort_t* ws    = (ushort_t*)d_ws;
  ushort_t* x0    = ws;                          // 4096*512
  ushort_t* x1    = x0    + 2097152;
  ushort_t* qkv   = x1    + 2097152;             // 4096*1536
  ushort_t* yb    = qkv   + 6291456;
  ushort_t* h1b   = yb    + 2097152;
  ushort_t* wprjb = h1b   + 2097152;             // fused arena [Wprj|Wq|Wk|Wv|W1|W2]
  ushort_t* wqkvb = wprjb + 262144;
  ushort_t* w1b   = wqkvb + 786432;
  ushort_t* w2b   = w1b   + 262144;              // 32000*512
  float*    bqkv  = (float*)(w2b + 16384000);    // 1536 f32

  cvt_all_kernel<<<2048, 256, 0, stream>>>(Wprj, Wq, Wk, Wv, W1, W2,
                                           bq_, bk_, bv_, wprjb, bqkv);

  embed_kernel<<<NROWS, 256, 0, stream>>>(ixs, tok, pos, x0);

  // x1 = x0 @ Wprj^T
  gemm_bt_kernel<0,0,0><<<32 * 4,   256, 0, stream>>>(x0,  wprjb, nullptr, x1,  NROWS, 512,   512);
  // qkv (fused q|k|v, N=1536)
  gemm_bt_kernel<1,0,0><<<32 * 12,  256, 0, stream>>>(x1,  wqkvb, bqkv,    qkv, NROWS, 1536,  512);
  // attention
  attn_kernel<<<dim3(32, 16), 256, 0, stream>>>(qkv, yb);
  // h1 = relu(y @ W1^T + b1)
  gemm_bt_kernel<1,1,0><<<32 * 4,   256, 0, stream>>>(yb,  w1b,   b1_,     h1b, NROWS, 512,   512);
  // out = relu(h1 @ W2^T + b2) -> f32, 8-phase-style 256^2 kernel
  gemm_big_kernel<<<16 * 125, 512, 0, stream>>>(h1b, w2b, b2_, out, NROWS, NVOCAB, 512);
}

// Round 4
// 400.110 us; speedup vs baseline: 1.1910x; 1.0061x over previous
//
#include <hip/hip_runtime.h>
#include <stdint.h>
#include <stddef.h>

#define TSEQ   2048
#define HDIM   512
#define NHEADS 8
#define HEADD  64
#define NVOCAB 32000
#define NROWS  4096   // B*T

typedef unsigned short ushort_t;
typedef __bf16 bf16x8 __attribute__((ext_vector_type(8)));
typedef float  f32x4  __attribute__((ext_vector_type(4)));
typedef unsigned short us8 __attribute__((ext_vector_type(8)));
typedef unsigned short us4 __attribute__((ext_vector_type(4)));
typedef unsigned short us2 __attribute__((ext_vector_type(2)));

__device__ __forceinline__ ushort_t f2bf(float f){
  union { float f; unsigned int u; } v; v.f = f;
  unsigned int u = v.u;
  u += 0x7FFFu + ((u >> 16) & 1u);   // RNE
  return (ushort_t)(u >> 16);
}

__device__ __forceinline__ void gload_lds16(const ushort_t* g, ushort_t* l){
  __builtin_amdgcn_global_load_lds(
      (const __attribute__((address_space(1))) void*)g,
      (__attribute__((address_space(3))) void*)l, 16, 0, 0);
}

// ---------------- fused f32 -> bf16 convert of all weights + bias concat ----------------
#define CVT_N4   4423680   // 5*65536 + 4096000
#define CVT_TOT  4424064   // + 384
__global__ void cvt_all_kernel(const float* __restrict__ Wprj, const float* __restrict__ Wq,
                               const float* __restrict__ Wk,   const float* __restrict__ Wv,
                               const float* __restrict__ W1,   const float* __restrict__ W2,
                               const float* __restrict__ bq,   const float* __restrict__ bk,
                               const float* __restrict__ bv,
                               ushort_t* __restrict__ wdst, float* __restrict__ bqkv){
  int stride = gridDim.x * blockDim.x;
  for (int i = blockIdx.x * blockDim.x + threadIdx.x; i < CVT_TOT; i += stride){
    if (i < CVT_N4){
      const float* src; int j;
      if (i < 327680){                       // the five 512x512 weights
        int w = i >> 16;                     // 0..4
        j = i & 65535;
        src = (w == 0) ? Wprj : (w == 1) ? Wq : (w == 2) ? Wk : (w == 3) ? Wv : W1;
      } else {
        j = i - 327680;
        src = W2;
      }
      float4 f = ((const float4*)src)[j];
      us4 o;
      o[0] = f2bf(f.x); o[1] = f2bf(f.y); o[2] = f2bf(f.z); o[3] = f2bf(f.w);
      ((us4*)wdst)[i] = o;
    } else {
      int j = i - CVT_N4;                    // 0..383 float4 of bqkv
      const float* src = (j < 128) ? bq : (j < 256) ? bk : bv;
      int jj = j & 127;
      ((float4*)bqkv)[j] = ((const float4*)src)[jj];
    }
  }
}

// ---------------- embedding: x0 = tok[ix] + pos ----------------
__global__ void embed_kernel(const int* __restrict__ ixs, const float* __restrict__ tok,
                             const float* __restrict__ pos, ushort_t* __restrict__ x0){
  const int r = blockIdx.x;            // 0..4095 (b*T + t)
  const int t = r & (TSEQ - 1);
  const int ix = ixs[r];
  const int j = threadIdx.x;           // 0..255, 2 floats each
  const float2 a = ((const float2*)(tok + (size_t)ix * HDIM))[j];
  const float2 p = ((const float2*)(pos + (size_t)t * HDIM))[j];
  us2 o; o[0] = f2bf(a.x + p.x); o[1] = f2bf(a.y + p.y);
  *(us2*)(x0 + (size_t)r * HDIM + j * 2) = o;
}

// ---------------- small GEMM (m97 structure): C[M,N] = A @ W^T (+bias)(+relu) ----------------
template<int HAS_BIAS, int RELU, int OUT_F32>
__global__ __launch_bounds__(256) void gemm_bt_kernel(
    const ushort_t* __restrict__ A, const ushort_t* __restrict__ W,
    const float* __restrict__ bias, void* __restrict__ outp,
    int M, int N, int K)
{
  __shared__ ushort_t As[128 * 64];
  __shared__ ushort_t Bs[128 * 64];
  const int tid  = threadIdx.x;
  const int wave = tid >> 6;
  const int lane = tid & 63;
  const int lr   = lane & 15;
  const int lg   = lane >> 4;
  const int nby  = M >> 7;
  const int by   = blockIdx.x % nby;
  const int bx   = blockIdx.x / nby;
  const int row0 = by << 7;
  const int col0 = bx << 7;
  const int wr   = wave >> 1, wc = wave & 1;

  f32x4 acc[4][4];
#pragma unroll
  for (int m = 0; m < 4; m++)
#pragma unroll
    for (int n = 0; n < 4; n++) acc[m][n] = (f32x4){0.f, 0.f, 0.f, 0.f};

  const int e    = tid * 8;
  const int srow = e >> 6;
  const int scol = e & 63;
  const ushort_t* gA = A + (size_t)(row0 + srow) * K + scol;
  const ushort_t* gB = W + (size_t)(col0 + srow) * K + scol;
  const int ldsbase = wave * 512;

  for (int kt = 0; kt < K; kt += 64){
#pragma unroll
    for (int p = 0; p < 4; p++){
      gload_lds16(gA + (size_t)(p * 32) * K + kt, &As[p * 2048 + ldsbase]);
      gload_lds16(gB + (size_t)(p * 32) * K + kt, &Bs[p * 2048 + ldsbase]);
    }
    __syncthreads();
#pragma unroll
    for (int kk = 0; kk < 64; kk += 32){
      bf16x8 af[4], bfr[4];
#pragma unroll
      for (int m = 0; m < 4; m++)
        af[m] = __builtin_bit_cast(bf16x8,
            *(const us8*)&As[(wr * 64 + m * 16 + lr) * 64 + kk + lg * 8]);
#pragma unroll
      for (int n = 0; n < 4; n++)
        bfr[n] = __builtin_bit_cast(bf16x8,
            *(const us8*)&Bs[(wc * 64 + n * 16 + lr) * 64 + kk + lg * 8]);
#pragma unroll
      for (int m = 0; m < 4; m++)
#pragma unroll
        for (int n = 0; n < 4; n++)
          acc[m][n] = __builtin_amdgcn_mfma_f32_16x16x32_bf16(af[m], bfr[n], acc[m][n], 0, 0, 0);
    }
    __syncthreads();
  }

#pragma unroll
  for (int n = 0; n < 4; n++){
    const int col = col0 + wc * 64 + n * 16 + lr;
    float bv = 0.f;
    if (HAS_BIAS) bv = bias[col];
#pragma unroll
    for (int m = 0; m < 4; m++){
      const int rowb = row0 + wr * 64 + m * 16 + lg * 4;
#pragma unroll
      for (int r = 0; r < 4; r++){
        float vv = acc[m][n][r] + bv;
        if (RELU) vv = fmaxf(vv, 0.f);
        const size_t o = (size_t)(rowb + r) * N + col;
        if (OUT_F32) ((float*)outp)[o] = vv;
        else         ((ushort_t*)outp)[o] = f2bf(vv);
      }
    }
  }
}

// ---------------- 8-phase-style 256x256 GEMM for the big vocab matmul ----------------
// out = relu(A[M,K=512] @ W[N,K]^T + bias), f32 out.
// 8 waves (2M x 4N), per-wave 128x64 output, BK=32, 16 K-tiles.
// Triple-buffered LDS (96 KB), depth-2 tile prefetch, counted vmcnt(4),
// raw s_barrier, setprio around MFMA.
// Swizzle: 16B chunk ^= key(row), key(r) = (r&3)^((r>>2)&3). With 64 B LDS rows
// this maps every 16-lane read group onto the 8 four-bank groups exactly 2x
// (2-way aliasing is free per m136); round-3's key=(r&3) left a 4-way conflict
// (lanes r,r+4,r+8,r+12 shared bank-base AND key -> LDS-bound inner loop).
// Same involution applied to pre-swizzled global source (LDS dest stays linear
// for global_load_lds per m104/m173).
#define NKT 16
__global__ __launch_bounds__(512, 2) void gemm_big_kernel(
    const ushort_t* __restrict__ A, const ushort_t* __restrict__ W,
    const float* __restrict__ bias, float* __restrict__ outp,
    int M, int N, int K)
{
  __shared__ ushort_t Asb[3][256 * 32];
  __shared__ ushort_t Bsb[3][256 * 32];
  const int tid  = threadIdx.x;
  const int wave = tid >> 6;            // 0..7
  const int lane = tid & 63;
  const int lr   = lane & 15;
  const int lg   = lane >> 4;
  const int wr   = wave >> 2;           // 0..1 (M)
  const int wc   = wave & 3;            // 0..3 (N)
  const int nby  = M >> 8;              // 16
  const int by   = blockIdx.x % nby;
  const int bx   = blockIdx.x / nby;
  const int row0 = by << 8;
  const int col0 = bx << 8;

  // staging: thread covers LDS rows rA, rA+128; chunk position tid&3;
  // global source chunk = pos ^ key(rA). key(rA+128)==key(rA).
  const int rA   = tid >> 2;            // 0..127
  const int csw  = ((tid & 3) ^ (rA & 3) ^ ((rA >> 2) & 3)) * 8;
  // read side: fragment row = (16-aligned) + lr  ->  key = (lr&3)^((lr>>2)&3)
  const int swzc = (lg ^ (lr & 3) ^ ((lr >> 2) & 3)) * 8;

  f32x4 acc[8][4];
#pragma unroll
  for (int m = 0; m < 8; m++)
#pragma unroll
    for (int n = 0; n < 4; n++) acc[m][n] = (f32x4){0.f, 0.f, 0.f, 0.f};

  // ---- prologue: stage tiles 0 and 1, wait for tile 0 ----
  {
    const ushort_t* gA = A + (size_t)(row0 + rA) * K + csw;
    const ushort_t* gW = W + (size_t)(col0 + rA) * K + csw;
#pragma unroll
    for (int t = 0; t < 2; t++){
      gload_lds16(gA + t * 32,                       &Asb[t][wave * 512]);
      gload_lds16(gA + (size_t)128 * K + t * 32,     &Asb[t][4096 + wave * 512]);
      gload_lds16(gW + t * 32,                       &Bsb[t][wave * 512]);
      gload_lds16(gW + (size_t)128 * K + t * 32,     &Bsb[t][4096 + wave * 512]);
    }
  }
  asm volatile("s_waitcnt vmcnt(4)" ::: "memory");
  __builtin_amdgcn_s_barrier();

  for (int t = 0; t < NKT; ++t){
    const ushort_t* Ac = &Asb[t % 3][0];
    const ushort_t* Bc = &Bsb[t % 3][0];
    ushort_t* An = &Asb[(t + 2) % 3][0];
    ushort_t* Bn = &Bsb[(t + 2) % 3][0];
    const bool pf = (t + 2 < NKT);
    const int kg = (t + 2) * 32;

    // ---------- phase 0: B-frags + A-frags m0..3 ; stage A of tile t+2 ----------
    bf16x8 bfr[4], af[4];
#pragma unroll
    for (int n = 0; n < 4; n++)
      bfr[n] = __builtin_bit_cast(bf16x8,
          *(const us8*)&Bc[(wc * 64 + n * 16 + lr) * 32 + swzc]);
#pragma unroll
    for (int q = 0; q < 4; q++)
      af[q] = __builtin_bit_cast(bf16x8,
          *(const us8*)&Ac[(wr * 128 + q * 16 + lr) * 32 + swzc]);
    if (pf){
      gload_lds16(A + (size_t)(row0 + rA) * K + kg + csw,       An + wave * 512);
      gload_lds16(A + (size_t)(row0 + rA + 128) * K + kg + csw, An + 4096 + wave * 512);
    }
    __builtin_amdgcn_s_barrier();
    asm volatile("s_waitcnt lgkmcnt(0)" ::: "memory");
    __builtin_amdgcn_sched_barrier(0);
    __builtin_amdgcn_s_setprio(1);
#pragma unroll
    for (int q = 0; q < 4; q++)
#pragma unroll
      for (int n = 0; n < 4; n++)
        acc[q][n] = __builtin_amdgcn_mfma_f32_16x16x32_bf16(af[q], bfr[n], acc[q][n], 0, 0, 0);
    __builtin_amdgcn_s_setprio(0);
    __builtin_amdgcn_sched_barrier(0);
    __builtin_amdgcn_s_barrier();

    // ---------- phase 1: A-frags m4..7 ; stage B of tile t+2 ----------
#pragma unroll
    for (int q = 0; q < 4; q++)
      af[q] = __builtin_bit_cast(bf16x8,
          *(const us8*)&Ac[(wr * 128 + (q + 4) * 16 + lr) * 32 + swzc]);
    if (pf){
      gload_lds16(W + (size_t)(col0 + rA) * K + kg + csw,       Bn + wave * 512);
      gload_lds16(W + (size_t)(col0 + rA + 128) * K + kg + csw, Bn + 4096 + wave * 512);
    }
    __builtin_amdgcn_s_barrier();
    asm volatile("s_waitcnt lgkmcnt(0)" ::: "memory");
    __builtin_amdgcn_sched_barrier(0);
    __builtin_amdgcn_s_setprio(1);
#pragma unroll
    for (int q = 0; q < 4; q++)
#pragma unroll
      for (int n = 0; n < 4; n++)
        acc[q + 4][n] = __builtin_amdgcn_mfma_f32_16x16x32_bf16(af[q], bfr[n], acc[q + 4][n], 0, 0, 0);
    __builtin_amdgcn_s_setprio(0);
    __builtin_amdgcn_sched_barrier(0);
    if (t < NKT - 2) { asm volatile("s_waitcnt vmcnt(4)" ::: "memory"); }
    else             { asm volatile("s_waitcnt vmcnt(0)" ::: "memory"); }
    __builtin_amdgcn_s_barrier();
  }

  // ---- epilogue ----
  float bvv[4];
#pragma unroll
  for (int n = 0; n < 4; n++) bvv[n] = bias[col0 + wc * 64 + n * 16 + lr];
#pragma unroll
  for (int m = 0; m < 8; m++)
#pragma unroll
    for (int n = 0; n < 4; n++){
      const size_t o0 = (size_t)(row0 + wr * 128 + m * 16 + lg * 4) * N
                      + (col0 + wc * 64 + n * 16 + lr);
#pragma unroll
      for (int r = 0; r < 4; r++)
        outp[o0 + (size_t)r * N] = fmaxf(acc[m][n][r] + bvv[n], 0.f);
    }
}

// ---------------- fused causal flash attention ----------------
// Heavy-first dispatch: qt = 31 - blockIdx.x so the 32-tile causal blocks
// launch first and light ones backfill the tail (32:1 work spread).
__global__ __launch_bounds__(256) void attn_kernel(
    const ushort_t* __restrict__ qkv, ushort_t* __restrict__ y)
{
  __shared__ ushort_t Ks[64 * 64];
  __shared__ ushort_t Vt[64 * 64];     // transposed: [d][key]
  __shared__ ushort_t Ps[4][16 * 64];
  const int qt   = 31 - blockIdx.x;
  const int hb   = blockIdx.y;
  const int b    = hb >> 3;
  const int h    = hb & 7;
  const int tid  = threadIdx.x;
  const int wave = tid >> 6, lane = tid & 63;
  const int lr   = lane & 15, lg = lane >> 4;
  const int ld   = 3 * HDIM;
  const size_t rowbase = (size_t)b * TSEQ;
  const ushort_t* kb = qkv + HDIM;
  const ushort_t* vb = qkv + 2 * HDIM;

  const int qrow = qt * 64 + wave * 16 + lr;
  const ushort_t* qp = qkv + (rowbase + qrow) * ld + h * HEADD;
  bf16x8 qf[2];
  qf[0] = __builtin_bit_cast(bf16x8, *(const us8*)&qp[lg * 8]);
  qf[1] = __builtin_bit_cast(bf16x8, *(const us8*)&qp[32 + lg * 8]);

  float m_run[4], l_run[4];
  f32x4 acc_o[4];
#pragma unroll
  for (int i = 0; i < 4; i++){ m_run[i] = -1e30f; l_run[i] = 0.f; acc_o[i] = (f32x4){0,0,0,0}; }

  const int e    = tid * 8;
  const int srow = e >> 6;
  const int scol = e & 63;
  const float scale = 0.04419417382415922f;   // 1/sqrt(512) (full H per reference!)

  for (int kt = 0; kt <= qt; ++kt){
    const ushort_t* gK = kb + (rowbase + kt * 64 + srow) * ld + h * HEADD + scol;
    gload_lds16(gK,                     &Ks[wave * 512]);
    gload_lds16(gK + (size_t)32 * ld,   &Ks[2048 + wave * 512]);
    const ushort_t* gV = vb + (rowbase + kt * 64 + srow) * ld + h * HEADD + scol;
    us8 v0 = *(const us8*)gV;
    us8 v1 = *(const us8*)(gV + (size_t)32 * ld);
#pragma unroll
    for (int j = 0; j < 8; j++){
      Vt[(scol + j) * 64 + srow]      = v0[j];
      Vt[(scol + j) * 64 + srow + 32] = v1[j];
    }
    __syncthreads();

    f32x4 s[4];
#pragma unroll
    for (int n = 0; n < 4; n++){
      s[n] = (f32x4){0, 0, 0, 0};
#pragma unroll
      for (int ks = 0; ks < 2; ks++){
        bf16x8 kf = __builtin_bit_cast(bf16x8,
            *(const us8*)&Ks[(n * 16 + lr) * 64 + ks * 32 + lg * 8]);
        s[n] = __builtin_amdgcn_mfma_f32_16x16x32_bf16(qf[ks], kf, s[n], 0, 0, 0);
      }
    }

    float sv[4][4];
    float tmax[4] = {-1e30f, -1e30f, -1e30f, -1e30f};
    const bool diag = (kt == qt);
#pragma unroll
    for (int n = 0; n < 4; n++)
#pragma unroll
      for (int r = 0; r < 4; r++){
        float x = s[n][r] * scale;
        if (diag && (n * 16 + lr) > (wave * 16 + lg * 4 + r)) x = -1e30f;
        sv[n][r] = x;
        tmax[r] = fmaxf(tmax[r], x);
      }
#pragma unroll
    for (int off = 1; off < 16; off <<= 1)
#pragma unroll
      for (int r = 0; r < 4; r++) tmax[r] = fmaxf(tmax[r], __shfl_xor(tmax[r], off));

    float alpha[4], psum[4];
#pragma unroll
    for (int r = 0; r < 4; r++){
      float mn = fmaxf(m_run[r], tmax[r]);
      alpha[r] = __expf(m_run[r] - mn);
      m_run[r] = mn;
      psum[r] = 0.f;
    }
    float p[4][4];
#pragma unroll
    for (int n = 0; n < 4; n++)
#pragma unroll
      for (int r = 0; r < 4; r++){ p[n][r] = __expf(sv[n][r] - m_run[r]); psum[r] += p[n][r]; }
#pragma unroll
    for (int off = 1; off < 16; off <<= 1)
#pragma unroll
      for (int r = 0; r < 4; r++) psum[r] += __shfl_xor(psum[r], off);
#pragma unroll
    for (int r = 0; r < 4; r++) l_run[r] = l_run[r] * alpha[r] + psum[r];
#pragma unroll
    for (int nd = 0; nd < 4; nd++)
#pragma unroll
      for (int r = 0; r < 4; r++) acc_o[nd][r] *= alpha[r];

#pragma unroll
    for (int n = 0; n < 4; n++)
#pragma unroll
      for (int r = 0; r < 4; r++)
        Ps[wave][(lg * 4 + r) * 64 + n * 16 + lr] = f2bf(p[n][r]);
    asm volatile("s_waitcnt lgkmcnt(0)" ::: "memory");
    bf16x8 pa[2];
    pa[0] = __builtin_bit_cast(bf16x8, *(const us8*)&Ps[wave][lr * 64 + lg * 8]);
    pa[1] = __builtin_bit_cast(bf16x8, *(const us8*)&Ps[wave][lr * 64 + 32 + lg * 8]);
#pragma unroll
    for (int nd = 0; nd < 4; nd++)
#pragma unroll
      for (int ks = 0; ks < 2; ks++){
        bf16x8 vf = __builtin_bit_cast(bf16x8,
            *(const us8*)&Vt[(nd * 16 + lr) * 64 + ks * 32 + lg * 8]);
        acc_o[nd] = __builtin_amdgcn_mfma_f32_16x16x32_bf16(pa[ks], vf, acc_o[nd], 0, 0, 0);
      }
    __syncthreads();
  }

  float inv[4];
#pragma unroll
  for (int r = 0; r < 4; r++) inv[r] = 1.f / l_run[r];
#pragma unroll
  for (int nd = 0; nd < 4; nd++)
#pragma unroll
    for (int r = 0; r < 4; r++){
      const int row_t = qt * 64 + wave * 16 + lg * 4 + r;
      y[(rowbase + row_t) * HDIM + h * HEADD + nd * 16 + lr] = f2bf(acc_o[nd][r] * inv[r]);
    }
}

// ---------------- launch ----------------
extern "C" void kernel_launch(void* const* d_in, const int* in_sizes, int n_in,
                              void* d_out, int out_size, void* d_ws, size_t ws_size,
                              hipStream_t stream)
{
  const int*   ixs  = (const int*)  d_in[0];
  const float* tok  = (const float*)d_in[1];
  const float* pos  = (const float*)d_in[2];
  const float* Wprj = (const float*)d_in[3];
  const float* Wq   = (const float*)d_in[4];
  const float* bq_  = (const float*)d_in[5];
  const float* Wk   = (const float*)d_in[6];
  const float* bk_  = (const float*)d_in[7];
  const float* Wv   = (const float*)d_in[8];
  const float* bv_  = (const float*)d_in[9];
  const float* W1   = (const float*)d_in[10];
  const float* b1_  = (const float*)d_in[11];
  const float* W2   = (const float*)d_in[12];
  const float* b2_  = (const float*)d_in[13];
  float* out = (float*)d_out;

  ushort_t* ws    = (ushort_t*)d_ws;
  ushort_t* x0    = ws;                          // 4096*512
  ushort_t* x1    = x0    + 2097152;
  ushort_t* qkv   = x1    + 2097152;             // 4096*1536
  ushort_t* yb    = qkv   + 6291456;
  ushort_t* h1b   = yb    + 2097152;
  ushort_t* wprjb = h1b   + 2097152;             // fused arena [Wprj|Wq|Wk|Wv|W1|W2]
  ushort_t* wqkvb = wprjb + 262144;
  ushort_t* w1b   = wqkvb + 786432;
  ushort_t* w2b   = w1b   + 262144;              // 32000*512
  float*    bqkv  = (float*)(w2b + 16384000);    // 1536 f32

  cvt_all_kernel<<<2048, 256, 0, stream>>>(Wprj, Wq, Wk, Wv, W1, W2,
                                           bq_, bk_, bv_, wprjb, bqkv);

  embed_kernel<<<NROWS, 256, 0, stream>>>(ixs, tok, pos, x0);

  // x1 = x0 @ Wprj^T
  gemm_bt_kernel<0,0,0><<<32 * 4,   256, 0, stream>>>(x0,  wprjb, nullptr, x1,  NROWS, 512,   512);
  // qkv (fused q|k|v, N=1536)
  gemm_bt_kernel<1,0,0><<<32 * 12,  256, 0, stream>>>(x1,  wqkvb, bqkv,    qkv, NROWS, 1536,  512);
  // attention
  attn_kernel<<<dim3(32, 16), 256, 0, stream>>>(qkv, yb);
  // h1 = relu(y @ W1^T + b1)
  gemm_bt_kernel<1,1,0><<<32 * 4,   256, 0, stream>>>(yb,  w1b,   b1_,     h1b, NROWS, 512,   512);
  // out = relu(h1 @ W2^T + b2) -> f32, 8-phase-style 256^2 kernel
  gemm_big_kernel<<<16 * 125, 512, 0, stream>>>(h1b, w2b, b2_, out, NROWS, NVOCAB, 512);
}